// Round 1
// baseline (18188.327 us; speedup 1.0000x reference)
//
#include <hip/hip_runtime.h>
#include <math.h>

#define NHID 1024
#define NSTEP 512
#define NB 32

// One workgroup per batch (batches are independent). Thread = neuron n.
// Per step: sparse accumulate over previous step's spike list (built via
// ballot+popcount compaction), then elementwise LIF/HRF update mirroring the
// reference's fp32 expression order exactly (contraction off).
__global__ __launch_bounds__(1024, 1)
void coesn_kernel(const float* __restrict__ x,
                  const float* __restrict__ x2h,
                  const float* __restrict__ h2h,
                  const float* __restrict__ bias,
                  const float* __restrict__ gamma_,
                  const float* __restrict__ eps_,
                  float* __restrict__ out,
                  float ref_decay)
{
#pragma clang fp contract(off)
    const int n = threadIdx.x;
    const int b = blockIdx.x;
    const int lane = n & 63;
    const int w = n >> 6;          // wave id within block (16 waves)

    __shared__ float xs[NSTEP];               // this batch's input sequence
    __shared__ unsigned short idx[NHID];      // compacted spike indices
    __shared__ int cnts[16];                  // per-wave spike counts

    if (n < NSTEP) xs[n] = x[b * NSTEP + n];

    const float w_in = x2h[n];
    const float bi   = bias[n];
    const float ga   = gamma_[n];
    const float ep   = eps_[n];

    float hy = 0.0f, hz = 0.0f, ref = 0.0f, lv = 0.0f;
    int scount = 0;
    int cnt = 0;                   // spike count of previous step

    __syncthreads();

    for (int t = 0; t < NSTEP; ++t) {
        // ---- recurrent drive: sum of h2h rows for spiking neurons ----
        float acc = 0.0f;
        #pragma unroll 8
        for (int k = 0; k < cnt; ++k) {
            int m = __builtin_amdgcn_readfirstlane((int)idx[k]); // wave-uniform
            acc += h2h[(m << 10) + n];     // coalesced row slice, scalar base
        }

        // ---- LIF neuron (exact reference expression order, no FMA) ----
        float xv  = xs[t];
        float p   = xv * w_in;
        float q   = p + acc;
        float cur = q + bi;

        float aa = (-lv) / 20.0f;          // -lif_v / LIF_TAU_M
        float bb = aa + cur;
        lv = lv + 0.042f * bb;             // DT = 0.042
        float ls = (lv > 0.05f) ? 1.0f : 0.0f;   // THETA_LIF
        lv = lv - ls * 0.05f;              // subtractive reset

        // ---- HRF oscillator ----
        float t1 = 35.0f * ls;             // SPIKE_GAIN
        float t2 = ga * hy;
        float t3 = ep * hz;
        float t4 = (t1 - t2) - t3;
        hz = hz + 0.042f * t4;
        hy = hy + 0.042f * hz;

        float sv = (hy - 0.05f) - ref;     // THETA_RF, refractory
        int sp = (sv > 0.0f) ? 1 : 0;
        float spf = sp ? 1.0f : 0.0f;
        float r1 = ref * ref_decay;
        ref = r1 + spf;
        scount += sp;

        // ---- build next step's compacted spike list ----
        unsigned long long bal = __ballot(sp);
        if (lane == 0) cnts[w] = __popcll(bal);
        __syncthreads();                   // cnts ready; old idx fully consumed

        int off = 0, total = 0;
        #pragma unroll
        for (int j = 0; j < 16; ++j) {
            int c = cnts[j];
            if (j < w) off += c;
            total += c;
        }
        if (sp) {
            unsigned long long below = (lane == 0) ? 0ull
                                     : (bal & ((1ull << lane) - 1ull));
            int pos = off + __popcll(below);
            idx[pos] = (unsigned short)((w << 6) + lane);
        }
        cnt = total;
        __syncthreads();                   // idx ready for next step
    }

    out[b * NHID + n] = (float)scount * (1.0f / 512.0f);
}

extern "C" void kernel_launch(void* const* d_in, const int* in_sizes, int n_in,
                              void* d_out, int out_size, void* d_ws, size_t ws_size,
                              hipStream_t stream) {
    const float* x     = (const float*)d_in[0];
    const float* x2h   = (const float*)d_in[1];
    const float* h2h   = (const float*)d_in[2];
    const float* bias  = (const float*)d_in[3];
    const float* gamma = (const float*)d_in[4];
    const float* eps   = (const float*)d_in[5];
    float* out = (float*)d_out;

    // REF_DECAY = float(np.exp(-DT/TAU_REF)) computed in f64 then cast, as ref
    float ref_decay = (float)exp(-(0.042 / 0.25));

    coesn_kernel<<<NB, NHID, 0, stream>>>(x, x2h, h2h, bias, gamma, eps, out,
                                          ref_decay);
}

// Round 2
// 15009.880 us; speedup vs baseline: 1.2118x; 1.2118x over previous
//
#include <hip/hip_runtime.h>
#include <math.h>

#define NHID   1024
#define NSTEP  512
#define NB     32
#define NSPLIT 8          // blocks per batch (column split)
#define COLS   128        // NHID / NSPLIT, also block size
#define NWORDS 16         // NHID / 64 spike-mask words

// 256 blocks (32 batches x 8 column-splits), 128 threads each.
// Per step: exchange 1024-bit spike mask via global double buffer +
// per-batch 8-block spin barrier (agent scope), then each block row-sums
// h2h over the spike list for its 128-column slice. Elementwise LIF/HRF
// math is bitwise-identical to the round-1 passing kernel (contract off,
// ascending-m single-accumulator row sum).
__global__ __launch_bounds__(COLS, 1)
void coesn_kernel(const float* __restrict__ x,
                  const float* __restrict__ x2h,
                  const float* __restrict__ h2h,
                  const float* __restrict__ bias,
                  const float* __restrict__ gamma_,
                  const float* __restrict__ eps_,
                  float* __restrict__ out,
                  unsigned long long* __restrict__ masks,  // [2][NB][NWORDS]
                  int* __restrict__ ctr,                   // [NB]
                  float ref_decay)
{
#pragma clang fp contract(off)
    const int tid  = threadIdx.x;
    const int blk  = blockIdx.x;
    const int b    = blk >> 3;      // batch
    const int j    = blk & 7;       // column split (== XCD id, round-robin)
    const int col  = j * COLS + tid;
    const int w    = tid >> 6;      // wave id in block (0..1)
    const int lane = tid & 63;

    __shared__ float xs[NSTEP];
    __shared__ unsigned short idx[NHID];
    __shared__ unsigned long long mw[NWORDS];
    __shared__ int cnts[NWORDS];

    for (int i = tid; i < NSTEP; i += COLS) xs[i] = x[b * NSTEP + i];

    const float w_in = x2h[col];
    const float bi   = bias[col];
    const float ga   = gamma_[col];
    const float ep   = eps_[col];

    float hy = 0.0f, hz = 0.0f, ref = 0.0f, lv = 0.0f;
    int scount = 0;
    int p = 0;                       // mask buffer parity (reads use p)

    __syncthreads();

    for (int t = 0; t < NSTEP; ++t) {
        // ---- read spike mask of step t-1 (all 1024 neurons, agent scope) ----
        if (tid < NWORDS) {
            unsigned long long v = __hip_atomic_load(
                &masks[(p * NB + b) * NWORDS + tid],
                __ATOMIC_ACQUIRE, __HIP_MEMORY_SCOPE_AGENT);
            mw[tid] = v;
            cnts[tid] = __popcll(v);
        }
        __syncthreads();

        // ---- expand mask -> ascending index list in LDS ----
        int total = 0;
        #pragma unroll
        for (int i = 0; i < NWORDS; ++i) total += cnts[i];
        if (tid < NWORDS) {
            int off = 0;
            for (int i = 0; i < tid; ++i) off += cnts[i];
            unsigned long long wv = mw[tid];
            while (wv) {
                int bit = __builtin_ctzll(wv);
                idx[off++] = (unsigned short)((tid << 6) + bit);
                wv &= wv - 1;
            }
        }
        __syncthreads();

        // ---- row-sum over spiking neurons, ascending order, single acc ----
        float acc = 0.0f;
        int k = 0;
        for (; k + 16 <= total; k += 16) {
            float v[16];
            #pragma unroll
            for (int u = 0; u < 16; ++u)
                v[u] = h2h[(((int)idx[k + u]) << 10) + col];  // independent loads
            #pragma unroll
            for (int u = 0; u < 16; ++u)
                acc += v[u];                                   // ordered adds
        }
        for (; k < total; ++k)
            acc += h2h[(((int)idx[k]) << 10) + col];

        // ---- LIF (exact reference expression order, no FMA) ----
        float xv  = xs[t];
        float pp  = xv * w_in;
        float q   = pp + acc;
        float cur = q + bi;

        float aa = (-lv) / 20.0f;
        float bb = aa + cur;
        lv = lv + 0.042f * bb;
        float ls = (lv > 0.05f) ? 1.0f : 0.0f;
        lv = lv - ls * 0.05f;

        // ---- HRF oscillator ----
        float t1 = 35.0f * ls;
        float t2 = ga * hy;
        float t3 = ep * hz;
        float t4 = (t1 - t2) - t3;
        hz = hz + 0.042f * t4;
        hy = hy + 0.042f * hz;

        float sv = (hy - 0.05f) - ref;
        int sp = (sv > 0.0f) ? 1 : 0;
        ref = ref * ref_decay + (sp ? 1.0f : 0.0f);
        scount += sp;

        // ---- publish this step's spikes, then per-batch barrier ----
        unsigned long long bal = __ballot(sp);
        p ^= 1;
        if (lane == 0) {
            __hip_atomic_store(&masks[(p * NB + b) * NWORDS + (j * 2 + w)], bal,
                               __ATOMIC_RELEASE, __HIP_MEMORY_SCOPE_AGENT);
        }
        __syncthreads();            // both waves' mask stores done (vmcnt drained)
        if (tid == 0) {
            __threadfence();        // belt-and-suspenders device fence
            __hip_atomic_fetch_add(&ctr[b], 1, __ATOMIC_ACQ_REL,
                                   __HIP_MEMORY_SCOPE_AGENT);
            const int target = NSPLIT * (t + 1);
            while (__hip_atomic_load(&ctr[b], __ATOMIC_ACQUIRE,
                                     __HIP_MEMORY_SCOPE_AGENT) < target)
                __builtin_amdgcn_s_sleep(1);
        }
        __syncthreads();
    }

    out[b * NHID + col] = (float)scount * (1.0f / 512.0f);
}

extern "C" void kernel_launch(void* const* d_in, const int* in_sizes, int n_in,
                              void* d_out, int out_size, void* d_ws, size_t ws_size,
                              hipStream_t stream) {
    const float* x     = (const float*)d_in[0];
    const float* x2h   = (const float*)d_in[1];
    const float* h2h   = (const float*)d_in[2];
    const float* bias  = (const float*)d_in[3];
    const float* gamma = (const float*)d_in[4];
    const float* eps   = (const float*)d_in[5];
    float* out = (float*)d_out;

    // ws layout: [0,128)   int ctr[NB]
    //            [256, 256+8192) u64 masks[2][NB][NWORDS]
    int* ctr = (int*)d_ws;
    unsigned long long* masks = (unsigned long long*)((char*)d_ws + 256);

    // zero barrier counters + both mask buffers (ws is poisoned each launch)
    hipMemsetAsync(d_ws, 0, 16384, stream);

    float ref_decay = (float)exp(-(0.042 / 0.25));

    coesn_kernel<<<NB * NSPLIT, COLS, 0, stream>>>(
        x, x2h, h2h, bias, gamma, eps, out, masks, ctr, ref_decay);
}

// Round 3
// 3988.339 us; speedup vs baseline: 4.5604x; 3.7634x over previous
//
#include <hip/hip_runtime.h>
#include <math.h>

#define NHID  1024
#define NSTEP 512
#define NB    32
#define NW    16   // waves per block
#define NC    16   // column chunks per wave (1024 / 64)

// One block per batch, 1024 threads = 16 waves. Wave w owns ROWS [64w,64w+64):
// its previous-step ballot (an SGPR) is exactly its row spike set -> zero
// communication for the sparse row-sum. Each wave accumulates partials for all
// 1024 columns (16 regs/lane, 16 independent loads per spiking row, immediate
// offsets, rows pipelined 2-deep for MLP). Cross-wave combine via LDS in
// ascending wave order (64-row-chunked ascending summation). Elementwise
// LIF/HRF math identical to round-1 passing kernel (contract off).
__global__ __launch_bounds__(1024, 1)
void coesn_kernel(const float* __restrict__ x,
                  const float* __restrict__ x2h,
                  const float* __restrict__ h2h,
                  const float* __restrict__ bias,
                  const float* __restrict__ gamma_,
                  const float* __restrict__ eps_,
                  float* __restrict__ out,
                  float ref_decay)
{
#pragma clang fp contract(off)
    const int tid  = threadIdx.x;
    const int b    = blockIdx.x;
    const int lane = tid & 63;
    const int w    = tid >> 6;

    __shared__ float xs[NSTEP];
    __shared__ float part[NW][NHID];   // 64 KB partial sums

    if (tid < NSTEP) xs[tid] = x[b * NSTEP + tid];

    const float w_in = x2h[tid];
    const float bi   = bias[tid];
    const float ga   = gamma_[tid];
    const float ep   = eps_[tid];

    float hy = 0.0f, hz = 0.0f, ref = 0.0f, lv = 0.0f;
    int scount = 0;
    unsigned long long bal = 0ull;     // this wave's rows' spikes (prev step)

    const float* hwave = h2h + ((size_t)(w << 6) << 10);  // row block 64w

    __syncthreads();

    for (int t = 0; t < NSTEP; ++t) {
        // ---- partial row-sum over this wave's spiking rows (ascending) ----
        float acc[NC];
        #pragma unroll
        for (int c = 0; c < NC; ++c) acc[c] = 0.0f;

        unsigned long long m = bal;
        while (m) {
            int rA = __builtin_ctzll(m); m &= m - 1ull;
            const float* pA = hwave + ((size_t)rA << 10);
            float vA[NC];
            #pragma unroll
            for (int c = 0; c < NC; ++c) vA[c] = pA[(c << 6) + lane];
            if (m) {
                int rB = __builtin_ctzll(m); m &= m - 1ull;
                const float* pB = hwave + ((size_t)rB << 10);
                float vB[NC];
                #pragma unroll
                for (int c = 0; c < NC; ++c) vB[c] = pB[(c << 6) + lane];
                #pragma unroll
                for (int c = 0; c < NC; ++c) acc[c] += vA[c];   // ordered:
                #pragma unroll
                for (int c = 0; c < NC; ++c) acc[c] += vB[c];   // A then B
            } else {
                #pragma unroll
                for (int c = 0; c < NC; ++c) acc[c] += vA[c];
            }
        }

        // ---- publish partials, reduce in ascending wave order ----
        #pragma unroll
        for (int c = 0; c < NC; ++c) part[w][(c << 6) + lane] = acc[c];
        __syncthreads();

        float rsum = 0.0f;
        #pragma unroll
        for (int ww = 0; ww < NW; ++ww) rsum += part[ww][tid];
        __syncthreads();               // all reads done before next-step writes

        // ---- LIF (exact reference expression order, no FMA) ----
        float xv  = xs[t];
        float pp  = xv * w_in;
        float q   = pp + rsum;
        float cur = q + bi;

        float aa = (-lv) / 20.0f;
        float bb = aa + cur;
        lv = lv + 0.042f * bb;
        float ls = (lv > 0.05f) ? 1.0f : 0.0f;
        lv = lv - ls * 0.05f;

        // ---- HRF oscillator ----
        float t1 = 35.0f * ls;
        float t2 = ga * hy;
        float t3 = ep * hz;
        float t4 = (t1 - t2) - t3;
        hz = hz + 0.042f * t4;
        hy = hy + 0.042f * hz;

        float sv = (hy - 0.05f) - ref;
        int sp = (sv > 0.0f) ? 1 : 0;
        ref = ref * ref_decay + (sp ? 1.0f : 0.0f);
        scount += sp;

        bal = __ballot(sp);            // next step's row set for THIS wave
    }

    out[b * NHID + tid] = (float)scount * (1.0f / 512.0f);
}

extern "C" void kernel_launch(void* const* d_in, const int* in_sizes, int n_in,
                              void* d_out, int out_size, void* d_ws, size_t ws_size,
                              hipStream_t stream) {
    const float* x     = (const float*)d_in[0];
    const float* x2h   = (const float*)d_in[1];
    const float* h2h   = (const float*)d_in[2];
    const float* bias  = (const float*)d_in[3];
    const float* gamma = (const float*)d_in[4];
    const float* eps   = (const float*)d_in[5];
    float* out = (float*)d_out;

    float ref_decay = (float)exp(-(0.042 / 0.25));

    coesn_kernel<<<NB, NHID, 0, stream>>>(x, x2h, h2h, bias, gamma, eps, out,
                                          ref_decay);
}

// Round 4
// 3847.182 us; speedup vs baseline: 4.7277x; 1.0367x over previous
//
#include <hip/hip_runtime.h>
#include <math.h>

#define NHID  1024
#define NSTEP 512
#define NB    32
#define NW    16   // waves per block

// One block per batch, 1024 threads = 16 waves. Wave w owns ROWS [64w,64w+64):
// its previous-step ballot (an SGPR) is exactly its row spike set. Rows are
// gathered with dwordx4 (lane l holds cols {c*256+4l..+3}, c=0..3): 4 VMEM
// instrs/row instead of 16. Per-column add order (ascending rows in wave,
// ascending waves in LDS reduce) is bitwise identical to the round-3 kernel.
__global__ __launch_bounds__(1024, 1)
void coesn_kernel(const float* __restrict__ x,
                  const float* __restrict__ x2h,
                  const float* __restrict__ h2h,
                  const float* __restrict__ bias,
                  const float* __restrict__ gamma_,
                  const float* __restrict__ eps_,
                  float* __restrict__ out,
                  float ref_decay)
{
#pragma clang fp contract(off)
    const int tid  = threadIdx.x;
    const int b    = blockIdx.x;
    const int lane = tid & 63;
    const int w    = tid >> 6;

    __shared__ float xs[NSTEP];
    __shared__ float part[NW][NHID];   // 64 KB partials

    if (tid < NSTEP) xs[tid] = x[b * NSTEP + tid];

    const float w_in = x2h[tid];
    const float bi   = bias[tid];
    const float ga   = gamma_[tid];
    const float ep   = eps_[tid];

    float hy = 0.0f, hz = 0.0f, ref = 0.0f, lv = 0.0f;
    int scount = 0;
    unsigned long long bal = 0ull;     // this wave's rows' spikes (prev step)

    // wave's 64-row block of h2h, as float4 rows (256 float4 per row)
    const float4* hw4 = (const float4*)(h2h + (((size_t)w << 6) << 10));

    __syncthreads();

    for (int t = 0; t < NSTEP; ++t) {
        float4 a0 = {0.f,0.f,0.f,0.f}, a1 = a0, a2 = a0, a3 = a0;

        unsigned long long m = bal;
        while (m) {
            int rA = __builtin_ctzll(m); m &= m - 1ull;
            const float4* pA = hw4 + ((size_t)rA << 8);
            float4 vA0 = pA[lane], vA1 = pA[64 + lane],
                   vA2 = pA[128 + lane], vA3 = pA[192 + lane];
            if (m) {
                int rB = __builtin_ctzll(m); m &= m - 1ull;
                const float4* pB = hw4 + ((size_t)rB << 8);
                float4 vB0 = pB[lane], vB1 = pB[64 + lane],
                       vB2 = pB[128 + lane], vB3 = pB[192 + lane];
                // ordered: row A then row B, per column
                a0.x += vA0.x; a0.y += vA0.y; a0.z += vA0.z; a0.w += vA0.w;
                a1.x += vA1.x; a1.y += vA1.y; a1.z += vA1.z; a1.w += vA1.w;
                a2.x += vA2.x; a2.y += vA2.y; a2.z += vA2.z; a2.w += vA2.w;
                a3.x += vA3.x; a3.y += vA3.y; a3.z += vA3.z; a3.w += vA3.w;
                a0.x += vB0.x; a0.y += vB0.y; a0.z += vB0.z; a0.w += vB0.w;
                a1.x += vB1.x; a1.y += vB1.y; a1.z += vB1.z; a1.w += vB1.w;
                a2.x += vB2.x; a2.y += vB2.y; a2.z += vB2.z; a2.w += vB2.w;
                a3.x += vB3.x; a3.y += vB3.y; a3.z += vB3.z; a3.w += vB3.w;
            } else {
                a0.x += vA0.x; a0.y += vA0.y; a0.z += vA0.z; a0.w += vA0.w;
                a1.x += vA1.x; a1.y += vA1.y; a1.z += vA1.z; a1.w += vA1.w;
                a2.x += vA2.x; a2.y += vA2.y; a2.z += vA2.z; a2.w += vA2.w;
                a3.x += vA3.x; a3.y += vA3.y; a3.z += vA3.z; a3.w += vA3.w;
            }
        }

        // ---- publish partials (b128), reduce in ascending wave order ----
        float4* pw = (float4*)part[w];
        pw[lane] = a0; pw[64 + lane] = a1; pw[128 + lane] = a2; pw[192 + lane] = a3;
        __syncthreads();

        float rsum = 0.0f;
        #pragma unroll
        for (int ww = 0; ww < NW; ++ww) rsum += part[ww][tid];
        __syncthreads();               // all reads done before next-step writes

        // ---- LIF (exact reference expression order, no FMA) ----
        float xv  = xs[t];
        float pp  = xv * w_in;
        float q   = pp + rsum;
        float cur = q + bi;

        float aa = (-lv) / 20.0f;
        float bb = aa + cur;
        lv = lv + 0.042f * bb;
        float ls = (lv > 0.05f) ? 1.0f : 0.0f;
        lv = lv - ls * 0.05f;

        // ---- HRF oscillator ----
        float t1 = 35.0f * ls;
        float t2 = ga * hy;
        float t3 = ep * hz;
        float t4 = (t1 - t2) - t3;
        hz = hz + 0.042f * t4;
        hy = hy + 0.042f * hz;

        float sv = (hy - 0.05f) - ref;
        int sp = (sv > 0.0f) ? 1 : 0;
        ref = ref * ref_decay + (sp ? 1.0f : 0.0f);
        scount += sp;

        bal = __ballot(sp);            // next step's row set for THIS wave
    }

    out[b * NHID + tid] = (float)scount * (1.0f / 512.0f);
}

extern "C" void kernel_launch(void* const* d_in, const int* in_sizes, int n_in,
                              void* d_out, int out_size, void* d_ws, size_t ws_size,
                              hipStream_t stream) {
    const float* x     = (const float*)d_in[0];
    const float* x2h   = (const float*)d_in[1];
    const float* h2h   = (const float*)d_in[2];
    const float* bias  = (const float*)d_in[3];
    const float* gamma = (const float*)d_in[4];
    const float* eps   = (const float*)d_in[5];
    float* out = (float*)d_out;

    float ref_decay = (float)exp(-(0.042 / 0.25));

    coesn_kernel<<<NB, NHID, 0, stream>>>(x, x2h, h2h, bias, gamma, eps, out,
                                          ref_decay);
}